// Round 12
// baseline (666.008 us; speedup 1.0000x reference)
//
#include <hip/hip_runtime.h>
#include <hip/hip_bf16.h>
#include <cstdint>

#define NNODES 100000
#define NEDGES 1000000
#define HDIM 64
#define ODIM 16
#define NB 8
#define NREL 90
#define KDIM (HDIM * NB)   // 512 = GEMM inner dim, k = i*8 + b
#define CPAD 16            // cursor padding: one counter per 64B line

typedef short short8 __attribute__((ext_vector_type(8)));
typedef float f32x4  __attribute__((ext_vector_type(4)));
union FragU { uint4 u; short8 s; };

__device__ __forceinline__ float asf(uint32_t u) { float f; __builtin_memcpy(&f, &u, 4); return f; }
__device__ __forceinline__ uint32_t asu(float f) { uint32_t u; __builtin_memcpy(&u, &f, 4); return u; }
__device__ __forceinline__ uint16_t f2bf(float f) {
    uint32_t x = asu(f);
    return (uint16_t)((x + 0x7FFFu + ((x >> 16) & 1u)) >> 16);
}
__device__ __forceinline__ uint32_t pack2(float lo, float hi) {
    return (uint32_t)f2bf(lo) | ((uint32_t)f2bf(hi) << 16);
}
__device__ __forceinline__ void fmaC(const float4& cA, const float4& cB, float xs,
                                     float* __restrict__ acc) {
    acc[0] = fmaf(cA.x, xs, acc[0]); acc[1] = fmaf(cA.y, xs, acc[1]);
    acc[2] = fmaf(cA.z, xs, acc[2]); acc[3] = fmaf(cA.w, xs, acc[3]);
    acc[4] = fmaf(cB.x, xs, acc[4]); acc[5] = fmaf(cB.y, xs, acc[5]);
    acc[6] = fmaf(cB.z, xs, acc[6]); acc[7] = fmaf(cB.w, xs, acc[7]);
}

// ---------------------------------------------------------------------------
// cast: f32 feats -> bf16 x  (4 elems/thread)
// ---------------------------------------------------------------------------
__global__ void cast_kernel(const float* __restrict__ in, uint16_t* __restrict__ out, int n4) {
    const int stride = (int)(gridDim.x * blockDim.x);
    for (int idx = (int)(blockIdx.x * blockDim.x + threadIdx.x); idx < n4; idx += stride) {
        float4 v = reinterpret_cast<const float4*>(in)[idx];
        uint2 p;
        p.x = pack2(v.x, v.y);
        p.y = pack2(v.z, v.w);
        reinterpret_cast<uint2*>(out)[idx] = p;
    }
}

// ---------------------------------------------------------------------------
// CSR build with LINE-PADDED counters (theory: 16 counters/64B line caused
// same-line atomic serialization -> scatter/hist throughput-bound).
// cnt/cursor live at stride CPAD ints = 1 counter per 64B line (6.4 MB,
// aliased into the dead G region; G is only written later by csr_agg).
// rec[e] = { src | (etype<<20), norm }  (8 B)
// ---------------------------------------------------------------------------
__global__ void zero_kernel(int* __restrict__ p, int n) {
    for (int i = (int)(blockIdx.x * blockDim.x + threadIdx.x); i < n;
         i += (int)(gridDim.x * blockDim.x)) p[i] = 0;
}

__global__ void hist_kernel(const int* __restrict__ dst, int* __restrict__ cnt, int nE) {
    for (int e = (int)(blockIdx.x * blockDim.x + threadIdx.x); e < nE;
         e += (int)(gridDim.x * blockDim.x)) atomicAdd(&cnt[dst[e] * CPAD], 1);
}

#define SCAN_B 512
__launch_bounds__(SCAN_B)
__global__ void scan_partial_kernel(const int* __restrict__ cnt, int* __restrict__ bsum, int n) {
    __shared__ int sh[SCAN_B];
    int id = (int)(blockIdx.x * SCAN_B + threadIdx.x);
    sh[threadIdx.x] = (id < n) ? cnt[id * CPAD] : 0;
    __syncthreads();
    for (int off = SCAN_B / 2; off > 0; off >>= 1) {
        if ((int)threadIdx.x < off) sh[threadIdx.x] += sh[threadIdx.x + off];
        __syncthreads();
    }
    if (threadIdx.x == 0) bsum[blockIdx.x] = sh[0];
}

__launch_bounds__(256)
__global__ void scan_base_kernel(const int* __restrict__ bsum, int* __restrict__ bbase,
                                 int* __restrict__ offs, int nblk, int nNodes) {
    __shared__ int sh[256];
    const int t = (int)threadIdx.x;
    int v = (t < nblk) ? bsum[t] : 0;
    sh[t] = v;
    __syncthreads();
    for (int off = 1; off < 256; off <<= 1) {
        int tmp = (t >= off) ? sh[t - off] : 0;
        __syncthreads();
        sh[t] += tmp;
        __syncthreads();
    }
    if (t < nblk) bbase[t] = sh[t] - v;       // exclusive base per block
    if (t == 255) offs[nNodes] = sh[255];     // grand total
}

__launch_bounds__(SCAN_B)
__global__ void scan_final_kernel(int* __restrict__ cnt, const int* __restrict__ bbase,
                                  int* __restrict__ offs, int n) {
    __shared__ int sh[SCAN_B];
    int id = (int)(blockIdx.x * SCAN_B + threadIdx.x);
    int v = (id < n) ? cnt[id * CPAD] : 0;
    sh[threadIdx.x] = v;
    __syncthreads();
    for (int off = 1; off < SCAN_B; off <<= 1) {
        int tmp = ((int)threadIdx.x >= off) ? sh[threadIdx.x - off] : 0;
        __syncthreads();
        sh[threadIdx.x] += tmp;
        __syncthreads();
    }
    if (id < n) {
        int excl = sh[threadIdx.x] - v + bbase[blockIdx.x];
        offs[id] = excl;
        cnt[id * CPAD] = excl;   // becomes the scatter cursor
    }
}

// Scatter: round-7 measured-better form (1 edge/thread grid-stride) + padded
// cursor. rec content identical; within-dst order atomic-race-determined.
__global__ void scatter_kernel(const int* __restrict__ src, const int* __restrict__ dst,
                               const int* __restrict__ et, const float* __restrict__ norm,
                               int* __restrict__ cursor, uint2* __restrict__ rec, int nE) {
    for (int e = (int)(blockIdx.x * blockDim.x + threadIdx.x); e < nE;
         e += (int)(gridDim.x * blockDim.x)) {
        int p = atomicAdd(&cursor[dst[e] * CPAD], 1);
        rec[p] = make_uint2((uint32_t)src[e] | ((uint32_t)et[e] << 20), asu(norm[e]));
    }
}

// ---------------------------------------------------------------------------
// Input-space aggregation (round-10 measured-improved form):
// G[d][i][b] = sum_{e in in(d)} norm_e*coeff[r_e,b]*x[src_e,i]
// HALF-WAVE per dst node; unroll-8 => 16 independent x-gathers per wave in
// flight. coeff staged in LDS. Edge/FMA order identical -> bit-identical G.
// ---------------------------------------------------------------------------
__launch_bounds__(256)
__global__ void csr_agg_kernel(const uint16_t* __restrict__ x,
                               const float* __restrict__ coeff,
                               const int* __restrict__ offs,
                               const uint2* __restrict__ rec,
                               uint16_t* __restrict__ G, int nNodes) {
    __shared__ __align__(16) float cS[NREL * NB];   // 2880 B
    for (int i = (int)threadIdx.x; i < NREL * NB; i += 256) cS[i] = coeff[i];
    __syncthreads();

    const int hl   = (int)threadIdx.x & 31;   // lane within half-wave
    const int hwid = (int)((blockIdx.x * blockDim.x + threadIdx.x) >> 5);
    const int nhw  = (int)((gridDim.x * blockDim.x) >> 5);

    for (int d = hwid; d < nNodes; d += nhw) {
        const int j0 = offs[d], j1 = offs[d + 1];
        float accL[NB] = {0.f, 0.f, 0.f, 0.f, 0.f, 0.f, 0.f, 0.f};  // i = 2*hl
        float accH[NB] = {0.f, 0.f, 0.f, 0.f, 0.f, 0.f, 0.f, 0.f};  // i = 2*hl+1
        int j = j0;
        for (; j + 8 <= j1; j += 8) {
            uint2 r[8];
#pragma unroll
            for (int u = 0; u < 8; u++) r[u] = rec[j + u];
            uint32_t w[8];
#pragma unroll
            for (int u = 0; u < 8; u++)
                w[u] = *reinterpret_cast<const uint32_t*>(
                    x + (size_t)(r[u].x & 0xFFFFFu) * HDIM + 2 * hl);
#pragma unroll
            for (int u = 0; u < 8; u++) {
                const float4 cA = *reinterpret_cast<const float4*>(cS + (r[u].x >> 20) * NB);
                const float4 cB = *reinterpret_cast<const float4*>(cS + (r[u].x >> 20) * NB + 4);
                const float nm = asf(r[u].y);
                fmaC(cA, cB, asf(w[u] << 16) * nm, accL);
                fmaC(cA, cB, asf(w[u] & 0xFFFF0000u) * nm, accH);
            }
        }
        for (; j < j1; j++) {
            const uint2 r0 = rec[j];
            const uint32_t w0 = *reinterpret_cast<const uint32_t*>(
                x + (size_t)(r0.x & 0xFFFFFu) * HDIM + 2 * hl);
            const float4 cA = *reinterpret_cast<const float4*>(cS + (r0.x >> 20) * NB);
            const float4 cB = *reinterpret_cast<const float4*>(cS + (r0.x >> 20) * NB + 4);
            const float nm = asf(r0.y);
            fmaC(cA, cB, asf(w0 << 16) * nm, accL);
            fmaC(cA, cB, asf(w0 & 0xFFFF0000u) * nm, accH);
        }
        // lane hl owns k = 16*hl .. 16*hl+15 (i=2hl -> b0..7, i=2hl+1 -> b0..7)
        uint4 lo, hi;
        lo.x = pack2(accL[0], accL[1]); lo.y = pack2(accL[2], accL[3]);
        lo.z = pack2(accL[4], accL[5]); lo.w = pack2(accL[6], accL[7]);
        hi.x = pack2(accH[0], accH[1]); hi.y = pack2(accH[2], accH[3]);
        hi.z = pack2(accH[4], accH[5]); hi.w = pack2(accH[6], accH[7]);
        uint16_t* gp = G + (size_t)d * KDIM + hl * 16;
        *reinterpret_cast<uint4*>(gp)     = lo;
        *reinterpret_cast<uint4*>(gp + 8) = hi;
    }
}

// ---------------------------------------------------------------------------
// proj_hidden: 512-thread LDS-Wf MFMA GEMM. 8 waves share ONE 64KB Wf copy
// (proven round-0 frag layout); wave w owns 16 rows and reuses each A-frag
// across ALL 4 o-tiles -> G read exactly once (was 4x in the register-panel
// version: each wave re-read the whole tile for its single o-tile).
// launch_bounds(512,4): VGPR cap 128 (need ~64, no spill); 128KB LDS ->
// 2 blocks/CU = 16 waves/CU. Inner loop identical to round-0 proven proj
// -> bit-identical output.
// ---------------------------------------------------------------------------
__launch_bounds__(512, 4)
__global__ void proj_hidden_kernel(const uint16_t* __restrict__ G,
                                   const float* __restrict__ bases,
                                   const float* __restrict__ bias,
                                   uint16_t* __restrict__ xout, int nNodes) {
    constexpr int OT = HDIM / 16;       // 4 o-tiles
    __shared__ __align__(16) uint16_t Wf[16 * OT * 64 * 8];   // 64 KB

    const int t    = (int)threadIdx.x;
    const int lane = t & 63;
    const int w    = t >> 6;            // 0..7: row-group of this wave
    const int q    = lane >> 4;
    const int c    = lane & 15;

    for (int idx = t; idx < 16 * OT * 64 * 8; idx += 512) {
        int j    = idx & 7;
        int ln   = (idx >> 3) & 63;
        int rest = idx >> 9;            // kb*OT + ot
        int ot   = rest & (OT - 1);
        int kb   = rest >> 2;
        int k    = kb * 32 + (ln >> 4) * 8 + j;
        int o    = ot * 16 + (ln & 15);
        int i    = k >> 3, b = k & 7;
        Wf[idx] = f2bf(bases[(size_t)(b * HDIM + i) * HDIM + o]);
    }
    __syncthreads();

    float bv[OT];
#pragma unroll
    for (int ot = 0; ot < OT; ot++) bv[ot] = bias[ot * 16 + c];

    const int nTiles = (nNodes + 127) / 128;
    for (int tile = (int)blockIdx.x; tile < nTiles; tile += (int)gridDim.x) {
        const int n0w = tile * 128 + w * 16;
        int arow = n0w + c;
        if (arow > nNodes - 1) arow = nNodes - 1;
        const uint16_t* gp = G + (size_t)arow * KDIM + q * 8;

        f32x4 acc[OT];
#pragma unroll
        for (int ot = 0; ot < OT; ot++) acc[ot] = {0.f, 0.f, 0.f, 0.f};

#pragma unroll
        for (int kb = 0; kb < 16; kb++) {
            FragU a;
            a.u = *reinterpret_cast<const uint4*>(gp + kb * 32);
#pragma unroll
            for (int ot = 0; ot < OT; ot++) {
                FragU b;
                b.u = *reinterpret_cast<const uint4*>(Wf + ((kb * OT + ot) * 64 + lane) * 8);
                acc[ot] = __builtin_amdgcn_mfma_f32_16x16x32_bf16(a.s, b.s, acc[ot], 0, 0, 0);
            }
        }

#pragma unroll
        for (int r = 0; r < 4; r++) {
            const int node = n0w + q * 4 + r;
            if (node < nNodes) {
#pragma unroll
                for (int ot = 0; ot < OT; ot++) {
                    float v = fmaxf(acc[ot][r] + bv[ot], 0.f);
                    xout[(size_t)node * HDIM + ot * 16 + c] = f2bf(v);
                }
            }
        }
    }
}

// ---------------------------------------------------------------------------
// proj_out: register-resident B-panel (measured good): 512x16 bf16 panel =
// 64 VGPR/lane; each wave reads distinct rows -> G read once. Unchanged.
// ---------------------------------------------------------------------------
__launch_bounds__(256, 3)
__global__ void proj_out_kernel(const uint16_t* __restrict__ G,
                                const float* __restrict__ bases,
                                const float* __restrict__ bias,
                                float* __restrict__ out, int nNodes) {
    const int t    = (int)threadIdx.x;
    const int lane = t & 63;
    const int w    = t >> 6;            // wave = node-group (0..3), single o-tile
    const int q    = lane >> 4;
    const int c    = lane & 15;

    FragU bf[16];
#pragma unroll
    for (int kb = 0; kb < 16; kb++) {
#pragma unroll
        for (int j = 0; j < 8; j++) {
            const int k = kb * 32 + q * 8 + j;
            const int i = k >> 3, b = k & 7;
            bf[kb].s[j] = (short)f2bf(bases[(size_t)(b * HDIM + i) * ODIM + c]);
        }
    }
    const float bv = bias[c];

    const int nTiles = (nNodes + 63) / 64;
    for (int tile = (int)blockIdx.x; tile < nTiles; tile += (int)gridDim.x) {
        int arow = tile * 64 + w * 16 + c;
        if (arow > nNodes - 1) arow = nNodes - 1;
        const uint16_t* gp = G + (size_t)arow * KDIM + q * 8;

        f32x4 acc = {0.f, 0.f, 0.f, 0.f};
#pragma unroll
        for (int kb = 0; kb < 16; kb++) {
            FragU a;
            a.u = *reinterpret_cast<const uint4*>(gp + kb * 32);
            acc = __builtin_amdgcn_mfma_f32_16x16x32_bf16(a.s, bf[kb].s, acc, 0, 0, 0);
        }

        const int nbase = tile * 64 + w * 16 + q * 4;
#pragma unroll
        for (int r = 0; r < 4; r++) {
            const int node = nbase + r;
            if (node < nNodes) out[(size_t)node * ODIM + c] = acc[r] + bv;
        }
    }
}

extern "C" void kernel_launch(void* const* d_in, const int* in_sizes, int n_in,
                              void* d_out, int out_size, void* d_ws, size_t ws_size,
                              hipStream_t stream) {
    const float* feats  = (const float*)d_in[0];
    const float* coeff0 = (const float*)d_in[1];
    const float* bases0 = (const float*)d_in[2];
    const float* bias0  = (const float*)d_in[3];
    const float* coeff1 = (const float*)d_in[4];
    const float* bases1 = (const float*)d_in[5];
    const float* bias1  = (const float*)d_in[6];
    const float* coeff2 = (const float*)d_in[7];
    const float* bases2 = (const float*)d_in[8];
    const float* bias2  = (const float*)d_in[9];
    const int*   src    = (const int*)d_in[10];
    const int*   dst    = (const int*)d_in[11];
    const int*   etype  = (const int*)d_in[12];
    const float* norm   = (const float*)d_in[13];
    float* out = (float*)d_out;

    char* base = (char*)d_ws;
    // layout: G 102.4MB | x 12.8MB | offs | (old cursor hole) | bsum | bbase | rec 8MB
    // Padded cursor (NNODES*CPAD*4 = 6.4MB) ALIASES the start of G: it is
    // dead before csr_agg first writes G (stream-ordered).
    uint16_t* G = (uint16_t*)base;
    int* curs   = (int*)base;                                          // aliased, 6.4MB
    uint16_t* x = (uint16_t*)(base + (size_t)NNODES * KDIM * 2);       // +102,400,000
    const size_t OFF_OFFS  = 115200000;
    const size_t OFF_BSUM  = OFF_OFFS + 800032;
    const size_t OFF_BBASE = OFF_BSUM + 1024;
    const size_t OFF_REC   = OFF_BBASE + 1024;                         // ~116 MB
    int*   offs  = (int*)(base + OFF_OFFS);
    int*   bsum  = (int*)(base + OFF_BSUM);
    int*   bbase = (int*)(base + OFF_BBASE);
    uint2* rec   = (uint2*)(base + OFF_REC);

    const int nblk = (NNODES + SCAN_B - 1) / SCAN_B;   // 196 <= 256

    // ---- CSR build (graph identical across layers; built once per call)
    hipLaunchKernelGGL(zero_kernel, dim3(2048), dim3(256), 0, stream, curs, NNODES * CPAD);
    hipLaunchKernelGGL(hist_kernel, dim3(2048), dim3(256), 0, stream, dst, curs, NEDGES);
    hipLaunchKernelGGL(scan_partial_kernel, dim3(nblk), dim3(SCAN_B), 0, stream, curs, bsum, NNODES);
    hipLaunchKernelGGL(scan_base_kernel, dim3(1), dim3(256), 0, stream, bsum, bbase, offs, nblk, NNODES);
    hipLaunchKernelGGL(scan_final_kernel, dim3(nblk), dim3(SCAN_B), 0, stream, curs, bbase, offs, NNODES);
    hipLaunchKernelGGL(scatter_kernel, dim3(2048), dim3(256), 0, stream,
                       src, dst, etype, norm, curs, rec, NEDGES);

    // ---- x0 = bf16(feats)
    hipLaunchKernelGGL(cast_kernel, dim3(2048), dim3(256), 0, stream,
                       feats, x, NNODES * HDIM / 4);

    // ---- Layer 0
    hipLaunchKernelGGL(csr_agg_kernel, dim3(2048), dim3(256), 0, stream,
                       x, coeff0, offs, rec, G, NNODES);
    hipLaunchKernelGGL(proj_hidden_kernel, dim3(512), dim3(512), 0, stream,
                       G, bases0, bias0, x, NNODES);
    // ---- Layer 1
    hipLaunchKernelGGL(csr_agg_kernel, dim3(2048), dim3(256), 0, stream,
                       x, coeff1, offs, rec, G, NNODES);
    hipLaunchKernelGGL(proj_hidden_kernel, dim3(512), dim3(512), 0, stream,
                       G, bases1, bias1, x, NNODES);
    // ---- Layer 2
    hipLaunchKernelGGL(csr_agg_kernel, dim3(2048), dim3(256), 0, stream,
                       x, coeff2, offs, rec, G, NNODES);
    hipLaunchKernelGGL(proj_out_kernel, dim3(1024), dim3(256), 0, stream,
                       G, bases2, bias2, out, NNODES);
}

// Round 15
// 448.499 us; speedup vs baseline: 1.4850x; 1.4850x over previous
//
#include <hip/hip_runtime.h>
#include <hip/hip_bf16.h>
#include <cstdint>

#define NNODES 100000
#define NEDGES 1000000
#define HDIM 64
#define ODIM 16
#define NB 8
#define NREL 90
#define KDIM (HDIM * NB)   // 512 = GEMM inner dim, k = i*8 + b
#define CPAD 16            // cursor padding: one counter per 64B line

typedef short short8 __attribute__((ext_vector_type(8)));
typedef float f32x4  __attribute__((ext_vector_type(4)));
union FragU { uint4 u; short8 s; };

__device__ __forceinline__ float asf(uint32_t u) { float f; __builtin_memcpy(&f, &u, 4); return f; }
__device__ __forceinline__ uint32_t asu(float f) { uint32_t u; __builtin_memcpy(&u, &f, 4); return u; }
__device__ __forceinline__ uint16_t f2bf(float f) {
    uint32_t x = asu(f);
    return (uint16_t)((x + 0x7FFFu + ((x >> 16) & 1u)) >> 16);
}
__device__ __forceinline__ uint32_t pack2(float lo, float hi) {
    return (uint32_t)f2bf(lo) | ((uint32_t)f2bf(hi) << 16);
}
__device__ __forceinline__ void fmaC(const float4& cA, const float4& cB, float xs,
                                     float* __restrict__ acc) {
    acc[0] = fmaf(cA.x, xs, acc[0]); acc[1] = fmaf(cA.y, xs, acc[1]);
    acc[2] = fmaf(cA.z, xs, acc[2]); acc[3] = fmaf(cA.w, xs, acc[3]);
    acc[4] = fmaf(cB.x, xs, acc[4]); acc[5] = fmaf(cB.y, xs, acc[5]);
    acc[6] = fmaf(cB.z, xs, acc[6]); acc[7] = fmaf(cB.w, xs, acc[7]);
}

// ---------------------------------------------------------------------------
// cast: f32 feats -> bf16 x  (4 elems/thread)
// ---------------------------------------------------------------------------
__global__ void cast_kernel(const float* __restrict__ in, uint16_t* __restrict__ out, int n4) {
    const int stride = (int)(gridDim.x * blockDim.x);
    for (int idx = (int)(blockIdx.x * blockDim.x + threadIdx.x); idx < n4; idx += stride) {
        float4 v = reinterpret_cast<const float4*>(in)[idx];
        uint2 p;
        p.x = pack2(v.x, v.y);
        p.y = pack2(v.z, v.w);
        reinterpret_cast<uint2*>(out)[idx] = p;
    }
}

// ---------------------------------------------------------------------------
// CSR build with line-padded counters (stride CPAD ints; aliased into the
// dead G region). rec[e] = { src | (etype<<20), norm }  (8 B)
// ---------------------------------------------------------------------------
__global__ void zero_kernel(int* __restrict__ p, int n) {
    for (int i = (int)(blockIdx.x * blockDim.x + threadIdx.x); i < n;
         i += (int)(gridDim.x * blockDim.x)) p[i] = 0;
}

__global__ void hist_kernel(const int* __restrict__ dst, int* __restrict__ cnt, int nE) {
    for (int e = (int)(blockIdx.x * blockDim.x + threadIdx.x); e < nE;
         e += (int)(gridDim.x * blockDim.x)) atomicAdd(&cnt[dst[e] * CPAD], 1);
}

#define SCAN_B 512
__launch_bounds__(SCAN_B)
__global__ void scan_partial_kernel(const int* __restrict__ cnt, int* __restrict__ bsum, int n) {
    __shared__ int sh[SCAN_B];
    int id = (int)(blockIdx.x * SCAN_B + threadIdx.x);
    sh[threadIdx.x] = (id < n) ? cnt[id * CPAD] : 0;
    __syncthreads();
    for (int off = SCAN_B / 2; off > 0; off >>= 1) {
        if ((int)threadIdx.x < off) sh[threadIdx.x] += sh[threadIdx.x + off];
        __syncthreads();
    }
    if (threadIdx.x == 0) bsum[blockIdx.x] = sh[0];
}

__launch_bounds__(256)
__global__ void scan_base_kernel(const int* __restrict__ bsum, int* __restrict__ bbase,
                                 int* __restrict__ offs, int nblk, int nNodes) {
    __shared__ int sh[256];
    const int t = (int)threadIdx.x;
    int v = (t < nblk) ? bsum[t] : 0;
    sh[t] = v;
    __syncthreads();
    for (int off = 1; off < 256; off <<= 1) {
        int tmp = (t >= off) ? sh[t - off] : 0;
        __syncthreads();
        sh[t] += tmp;
        __syncthreads();
    }
    if (t < nblk) bbase[t] = sh[t] - v;       // exclusive base per block
    if (t == 255) offs[nNodes] = sh[255];     // grand total
}

__launch_bounds__(SCAN_B)
__global__ void scan_final_kernel(int* __restrict__ cnt, const int* __restrict__ bbase,
                                  int* __restrict__ offs, int n) {
    __shared__ int sh[SCAN_B];
    int id = (int)(blockIdx.x * SCAN_B + threadIdx.x);
    int v = (id < n) ? cnt[id * CPAD] : 0;
    sh[threadIdx.x] = v;
    __syncthreads();
    for (int off = 1; off < SCAN_B; off <<= 1) {
        int tmp = ((int)threadIdx.x >= off) ? sh[threadIdx.x - off] : 0;
        __syncthreads();
        sh[threadIdx.x] += tmp;
        __syncthreads();
    }
    if (id < n) {
        int excl = sh[threadIdx.x] - v + bbase[blockIdx.x];
        offs[id] = excl;
        cnt[id * CPAD] = excl;   // becomes the scatter cursor
    }
}

// Scatter: 1 edge/thread grid-stride + padded cursor.
__global__ void scatter_kernel(const int* __restrict__ src, const int* __restrict__ dst,
                               const int* __restrict__ et, const float* __restrict__ norm,
                               int* __restrict__ cursor, uint2* __restrict__ rec, int nE) {
    for (int e = (int)(blockIdx.x * blockDim.x + threadIdx.x); e < nE;
         e += (int)(gridDim.x * blockDim.x)) {
        int p = atomicAdd(&cursor[dst[e] * CPAD], 1);
        rec[p] = make_uint2((uint32_t)src[e] | ((uint32_t)et[e] << 20), asu(norm[e]));
    }
}

// ---------------------------------------------------------------------------
// Input-space aggregation (round-10 measured-improved form):
// HALF-WAVE per dst node; unroll-8 => 16 independent x-gathers per wave in
// flight. coeff staged in LDS. Edge/FMA order identical -> bit-identical G.
// ---------------------------------------------------------------------------
__launch_bounds__(256)
__global__ void csr_agg_kernel(const uint16_t* __restrict__ x,
                               const float* __restrict__ coeff,
                               const int* __restrict__ offs,
                               const uint2* __restrict__ rec,
                               uint16_t* __restrict__ G, int nNodes) {
    __shared__ __align__(16) float cS[NREL * NB];   // 2880 B
    for (int i = (int)threadIdx.x; i < NREL * NB; i += 256) cS[i] = coeff[i];
    __syncthreads();

    const int hl   = (int)threadIdx.x & 31;   // lane within half-wave
    const int hwid = (int)((blockIdx.x * blockDim.x + threadIdx.x) >> 5);
    const int nhw  = (int)((gridDim.x * blockDim.x) >> 5);

    for (int d = hwid; d < nNodes; d += nhw) {
        const int j0 = offs[d], j1 = offs[d + 1];
        float accL[NB] = {0.f, 0.f, 0.f, 0.f, 0.f, 0.f, 0.f, 0.f};  // i = 2*hl
        float accH[NB] = {0.f, 0.f, 0.f, 0.f, 0.f, 0.f, 0.f, 0.f};  // i = 2*hl+1
        int j = j0;
        for (; j + 8 <= j1; j += 8) {
            uint2 r[8];
#pragma unroll
            for (int u = 0; u < 8; u++) r[u] = rec[j + u];
            uint32_t w[8];
#pragma unroll
            for (int u = 0; u < 8; u++)
                w[u] = *reinterpret_cast<const uint32_t*>(
                    x + (size_t)(r[u].x & 0xFFFFFu) * HDIM + 2 * hl);
#pragma unroll
            for (int u = 0; u < 8; u++) {
                const float4 cA = *reinterpret_cast<const float4*>(cS + (r[u].x >> 20) * NB);
                const float4 cB = *reinterpret_cast<const float4*>(cS + (r[u].x >> 20) * NB + 4);
                const float nm = asf(r[u].y);
                fmaC(cA, cB, asf(w[u] << 16) * nm, accL);
                fmaC(cA, cB, asf(w[u] & 0xFFFF0000u) * nm, accH);
            }
        }
        for (; j < j1; j++) {
            const uint2 r0 = rec[j];
            const uint32_t w0 = *reinterpret_cast<const uint32_t*>(
                x + (size_t)(r0.x & 0xFFFFFu) * HDIM + 2 * hl);
            const float4 cA = *reinterpret_cast<const float4*>(cS + (r0.x >> 20) * NB);
            const float4 cB = *reinterpret_cast<const float4*>(cS + (r0.x >> 20) * NB + 4);
            const float nm = asf(r0.y);
            fmaC(cA, cB, asf(w0 << 16) * nm, accL);
            fmaC(cA, cB, asf(w0 & 0xFFFF0000u) * nm, accH);
        }
        // lane hl owns k = 16*hl .. 16*hl+15 (i=2hl -> b0..7, i=2hl+1 -> b0..7)
        uint4 lo, hi;
        lo.x = pack2(accL[0], accL[1]); lo.y = pack2(accL[2], accL[3]);
        lo.z = pack2(accL[4], accL[5]); lo.w = pack2(accL[6], accL[7]);
        hi.x = pack2(accH[0], accH[1]); hi.y = pack2(accH[2], accH[3]);
        hi.z = pack2(accH[4], accH[5]); hi.w = pack2(accH[6], accH[7]);
        uint16_t* gp = G + (size_t)d * KDIM + hl * 16;
        *reinterpret_cast<uint4*>(gp)     = lo;
        *reinterpret_cast<uint4*>(gp + 8) = hi;
    }
}

// ---------------------------------------------------------------------------
// proj_hidden HYBRID: 256-thread blocks (>256-thr blocks spill: VGPR capped
// at 64 — measured rounds 4 & 12). Register-resident B-panel per wave
// (wave = o-tile, proven round-7 form) + 64-row G tile staged ONCE in LDS,
// shared by all 4 waves -> G HBM-read 1x (was 4x).
// LDS swizzle: 16B granule g of row r stored at g^(r&7) (bijective per row)
// -> A-frag reads (16 rows, same column) spread over 8 bank-groups.
// A values, MFMA order, epilogue identical to round-7 -> bit-identical out.
// launch_bounds(256,2): VGPR cap 256 (need ~110, no spill); 64KB LDS ->
// 2 blocks/CU = 8 waves/CU.
// ---------------------------------------------------------------------------
__launch_bounds__(256, 2)
__global__ void proj_hidden_kernel(const uint16_t* __restrict__ G,
                                   const float* __restrict__ bases,
                                   const float* __restrict__ bias,
                                   uint16_t* __restrict__ xout, int nNodes) {
    __shared__ __align__(16) uint4 Gs4[64 * 64];   // 64 rows x 64 granules = 64 KB

    const int t    = (int)threadIdx.x;
    const int lane = t & 63;
    const int ot   = t >> 6;            // wave = o-tile (0..3)
    const int q    = lane >> 4;
    const int c    = lane & 15;

    FragU bf[16];
#pragma unroll
    for (int kb = 0; kb < 16; kb++) {
#pragma unroll
        for (int j = 0; j < 8; j++) {
            const int k = kb * 32 + q * 8 + j;
            const int i = k >> 3, b = k & 7;
            bf[kb].s[j] = (short)f2bf(bases[(size_t)(b * HDIM + i) * HDIM + ot * 16 + c]);
        }
    }
    const float bv = bias[ot * 16 + c];

    const int nTiles = (nNodes + 63) / 64;
    for (int tile = (int)blockIdx.x; tile < nTiles; tile += (int)gridDim.x) {
        // ---- stage G tile (64 rows x 1024 B), swizzled granules
        for (int idx = t; idx < 64 * 64; idx += 256) {
            const int row = idx >> 6, g = idx & 63;
            int arow = tile * 64 + row;
            if (arow > nNodes - 1) arow = nNodes - 1;
            Gs4[(row << 6) | (g ^ (row & 7))] =
                *reinterpret_cast<const uint4*>(G + (size_t)arow * KDIM + g * 8);
        }
        __syncthreads();

        // ---- 4 row-groups per wave, A-frags from LDS
#pragma unroll
        for (int g = 0; g < 4; g++) {
            const int row = g * 16 + c;
            f32x4 acc = {0.f, 0.f, 0.f, 0.f};
#pragma unroll
            for (int kb = 0; kb < 16; kb++) {
                FragU a;
                a.u = Gs4[(row << 6) | ((kb * 4 + q) ^ (row & 7))];
                acc = __builtin_amdgcn_mfma_f32_16x16x32_bf16(a.s, bf[kb].s, acc, 0, 0, 0);
            }
            const int nbase = tile * 64 + g * 16 + q * 4;
#pragma unroll
            for (int r = 0; r < 4; r++) {
                const int node = nbase + r;
                if (node < nNodes) {
                    float v = fmaxf(acc[r] + bv, 0.f);
                    xout[(size_t)node * HDIM + ot * 16 + c] = f2bf(v);
                }
            }
        }
        __syncthreads();   // Gs4 reused next tile
    }
}

// ---------------------------------------------------------------------------
// proj_out: register-resident B-panel (measured good): each wave reads
// distinct rows -> G read once. Unchanged.
// ---------------------------------------------------------------------------
__launch_bounds__(256, 3)
__global__ void proj_out_kernel(const uint16_t* __restrict__ G,
                                const float* __restrict__ bases,
                                const float* __restrict__ bias,
                                float* __restrict__ out, int nNodes) {
    const int t    = (int)threadIdx.x;
    const int lane = t & 63;
    const int w    = t >> 6;            // wave = node-group (0..3), single o-tile
    const int q    = lane >> 4;
    const int c    = lane & 15;

    FragU bf[16];
#pragma unroll
    for (int kb = 0; kb < 16; kb++) {
#pragma unroll
        for (int j = 0; j < 8; j++) {
            const int k = kb * 32 + q * 8 + j;
            const int i = k >> 3, b = k & 7;
            bf[kb].s[j] = (short)f2bf(bases[(size_t)(b * HDIM + i) * ODIM + c]);
        }
    }
    const float bv = bias[c];

    const int nTiles = (nNodes + 63) / 64;
    for (int tile = (int)blockIdx.x; tile < nTiles; tile += (int)gridDim.x) {
        int arow = tile * 64 + w * 16 + c;
        if (arow > nNodes - 1) arow = nNodes - 1;
        const uint16_t* gp = G + (size_t)arow * KDIM + q * 8;

        f32x4 acc = {0.f, 0.f, 0.f, 0.f};
#pragma unroll
        for (int kb = 0; kb < 16; kb++) {
            FragU a;
            a.u = *reinterpret_cast<const uint4*>(gp + kb * 32);
            acc = __builtin_amdgcn_mfma_f32_16x16x32_bf16(a.s, bf[kb].s, acc, 0, 0, 0);
        }

        const int nbase = tile * 64 + w * 16 + q * 4;
#pragma unroll
        for (int r = 0; r < 4; r++) {
            const int node = nbase + r;
            if (node < nNodes) out[(size_t)node * ODIM + c] = acc[r] + bv;
        }
    }
}

extern "C" void kernel_launch(void* const* d_in, const int* in_sizes, int n_in,
                              void* d_out, int out_size, void* d_ws, size_t ws_size,
                              hipStream_t stream) {
    const float* feats  = (const float*)d_in[0];
    const float* coeff0 = (const float*)d_in[1];
    const float* bases0 = (const float*)d_in[2];
    const float* bias0  = (const float*)d_in[3];
    const float* coeff1 = (const float*)d_in[4];
    const float* bases1 = (const float*)d_in[5];
    const float* bias1  = (const float*)d_in[6];
    const float* coeff2 = (const float*)d_in[7];
    const float* bases2 = (const float*)d_in[8];
    const float* bias2  = (const float*)d_in[9];
    const int*   src    = (const int*)d_in[10];
    const int*   dst    = (const int*)d_in[11];
    const int*   etype  = (const int*)d_in[12];
    const float* norm   = (const float*)d_in[13];
    float* out = (float*)d_out;

    char* base = (char*)d_ws;
    // layout: G 102.4MB | x 12.8MB | offs | bsum | bbase | rec 8MB
    // Padded cursor (NNODES*CPAD*4 = 6.4MB) ALIASES the start of G: it is
    // dead before csr_agg first writes G (stream-ordered).
    uint16_t* G = (uint16_t*)base;
    int* curs   = (int*)base;                                          // aliased, 6.4MB
    uint16_t* x = (uint16_t*)(base + (size_t)NNODES * KDIM * 2);       // +102,400,000
    const size_t OFF_OFFS  = 115200000;
    const size_t OFF_BSUM  = OFF_OFFS + 800032;
    const size_t OFF_BBASE = OFF_BSUM + 1024;
    const size_t OFF_REC   = OFF_BBASE + 1024;                         // ~116 MB
    int*   offs  = (int*)(base + OFF_OFFS);
    int*   bsum  = (int*)(base + OFF_BSUM);
    int*   bbase = (int*)(base + OFF_BBASE);
    uint2* rec   = (uint2*)(base + OFF_REC);

    const int nblk = (NNODES + SCAN_B - 1) / SCAN_B;   // 196 <= 256

    // ---- CSR build (graph identical across layers; built once per call)
    hipLaunchKernelGGL(zero_kernel, dim3(2048), dim3(256), 0, stream, curs, NNODES * CPAD);
    hipLaunchKernelGGL(hist_kernel, dim3(2048), dim3(256), 0, stream, dst, curs, NEDGES);
    hipLaunchKernelGGL(scan_partial_kernel, dim3(nblk), dim3(SCAN_B), 0, stream, curs, bsum, NNODES);
    hipLaunchKernelGGL(scan_base_kernel, dim3(1), dim3(256), 0, stream, bsum, bbase, offs, nblk, NNODES);
    hipLaunchKernelGGL(scan_final_kernel, dim3(nblk), dim3(SCAN_B), 0, stream, curs, bbase, offs, NNODES);
    hipLaunchKernelGGL(scatter_kernel, dim3(2048), dim3(256), 0, stream,
                       src, dst, etype, norm, curs, rec, NEDGES);

    // ---- x0 = bf16(feats)
    hipLaunchKernelGGL(cast_kernel, dim3(2048), dim3(256), 0, stream,
                       feats, x, NNODES * HDIM / 4);

    // ---- Layer 0
    hipLaunchKernelGGL(csr_agg_kernel, dim3(2048), dim3(256), 0, stream,
                       x, coeff0, offs, rec, G, NNODES);
    hipLaunchKernelGGL(proj_hidden_kernel, dim3(1024), dim3(256), 0, stream,
                       G, bases0, bias0, x, NNODES);
    // ---- Layer 1
    hipLaunchKernelGGL(csr_agg_kernel, dim3(2048), dim3(256), 0, stream,
                       x, coeff1, offs, rec, G, NNODES);
    hipLaunchKernelGGL(proj_hidden_kernel, dim3(1024), dim3(256), 0, stream,
                       G, bases1, bias1, x, NNODES);
    // ---- Layer 2
    hipLaunchKernelGGL(csr_agg_kernel, dim3(2048), dim3(256), 0, stream,
                       x, coeff2, offs, rec, G, NNODES);
    hipLaunchKernelGGL(proj_out_kernel, dim3(1024), dim3(256), 0, stream,
                       G, bases2, bias2, out, NNODES);
}

// Round 16
// 428.276 us; speedup vs baseline: 1.5551x; 1.0472x over previous
//
#include <hip/hip_runtime.h>
#include <hip/hip_bf16.h>
#include <cstdint>

#define NNODES 100000
#define NEDGES 1000000
#define HDIM 64
#define ODIM 16
#define NB 8
#define NREL 90
#define KDIM (HDIM * NB)   // 512 = GEMM inner dim, k = i*8 + b
#define CPAD 16            // cursor padding: one counter per 64B line
#define NRANGE 8           // dst ranges (== XCD count heuristic)
#define RANGE ((NNODES + NRANGE - 1) / NRANGE)   // 12500 nodes/range

typedef short short8 __attribute__((ext_vector_type(8)));
typedef float f32x4  __attribute__((ext_vector_type(4)));
union FragU { uint4 u; short8 s; };

__device__ __forceinline__ float asf(uint32_t u) { float f; __builtin_memcpy(&f, &u, 4); return f; }
__device__ __forceinline__ uint32_t asu(float f) { uint32_t u; __builtin_memcpy(&u, &f, 4); return u; }
__device__ __forceinline__ uint16_t f2bf(float f) {
    uint32_t x = asu(f);
    return (uint16_t)((x + 0x7FFFu + ((x >> 16) & 1u)) >> 16);
}
__device__ __forceinline__ uint32_t pack2(float lo, float hi) {
    return (uint32_t)f2bf(lo) | ((uint32_t)f2bf(hi) << 16);
}
__device__ __forceinline__ void fmaC(const float4& cA, const float4& cB, float xs,
                                     float* __restrict__ acc) {
    acc[0] = fmaf(cA.x, xs, acc[0]); acc[1] = fmaf(cA.y, xs, acc[1]);
    acc[2] = fmaf(cA.z, xs, acc[2]); acc[3] = fmaf(cA.w, xs, acc[3]);
    acc[4] = fmaf(cB.x, xs, acc[4]); acc[5] = fmaf(cB.y, xs, acc[5]);
    acc[6] = fmaf(cB.z, xs, acc[6]); acc[7] = fmaf(cB.w, xs, acc[7]);
}

// ---------------------------------------------------------------------------
// cast: f32 feats -> bf16 x  (4 elems/thread)
// ---------------------------------------------------------------------------
__global__ void cast_kernel(const float* __restrict__ in, uint16_t* __restrict__ out, int n4) {
    const int stride = (int)(gridDim.x * blockDim.x);
    for (int idx = (int)(blockIdx.x * blockDim.x + threadIdx.x); idx < n4; idx += stride) {
        float4 v = reinterpret_cast<const float4*>(in)[idx];
        uint2 p;
        p.x = pack2(v.x, v.y);
        p.y = pack2(v.z, v.w);
        reinterpret_cast<uint2*>(out)[idx] = p;
    }
}

// ---------------------------------------------------------------------------
// CSR build, XCD-PARTITIONED: block b -> dst-range r = b&7, edge-chunk b>>3.
// All atomics/stores for range r issue from blocks with bid%8==r, which the
// round-robin dispatch maps to one XCD -> cursor lines and rec lines stay in
// that XCD's L2 (atomics don't bounce via HBM; rec 64B lines fill fully
// before eviction -> ~1x write amplification instead of ~8x).
// rec content per dst is set-identical to before (within-dst order was
// already atomic-race-determined).
// ---------------------------------------------------------------------------
__global__ void zero_kernel(int* __restrict__ p, int n) {
    for (int i = (int)(blockIdx.x * blockDim.x + threadIdx.x); i < n;
         i += (int)(gridDim.x * blockDim.x)) p[i] = 0;
}

__global__ void hist_kernel(const int* __restrict__ dst, int* __restrict__ cnt, int nE) {
    const int r     = (int)blockIdx.x & (NRANGE - 1);
    const int chunk = (int)blockIdx.x >> 3;
    const int nchk  = (int)gridDim.x >> 3;
    const int CH    = (nE + nchk - 1) / nchk;
    const int lo    = r * RANGE;
    const int hi    = (lo + RANGE < NNODES) ? lo + RANGE : NNODES;
    const int e1    = ((chunk + 1) * CH < nE) ? (chunk + 1) * CH : nE;
    for (int e = chunk * CH + (int)threadIdx.x; e < e1; e += 256) {
        const int d = dst[e];
        if (d >= lo && d < hi) atomicAdd(&cnt[d * CPAD], 1);
    }
}

#define SCAN_B 512
__launch_bounds__(SCAN_B)
__global__ void scan_partial_kernel(const int* __restrict__ cnt, int* __restrict__ bsum, int n) {
    __shared__ int sh[SCAN_B];
    int id = (int)(blockIdx.x * SCAN_B + threadIdx.x);
    sh[threadIdx.x] = (id < n) ? cnt[id * CPAD] : 0;
    __syncthreads();
    for (int off = SCAN_B / 2; off > 0; off >>= 1) {
        if ((int)threadIdx.x < off) sh[threadIdx.x] += sh[threadIdx.x + off];
        __syncthreads();
    }
    if (threadIdx.x == 0) bsum[blockIdx.x] = sh[0];
}

__launch_bounds__(256)
__global__ void scan_base_kernel(const int* __restrict__ bsum, int* __restrict__ bbase,
                                 int* __restrict__ offs, int nblk, int nNodes) {
    __shared__ int sh[256];
    const int t = (int)threadIdx.x;
    int v = (t < nblk) ? bsum[t] : 0;
    sh[t] = v;
    __syncthreads();
    for (int off = 1; off < 256; off <<= 1) {
        int tmp = (t >= off) ? sh[t - off] : 0;
        __syncthreads();
        sh[t] += tmp;
        __syncthreads();
    }
    if (t < nblk) bbase[t] = sh[t] - v;       // exclusive base per block
    if (t == 255) offs[nNodes] = sh[255];     // grand total
}

__launch_bounds__(SCAN_B)
__global__ void scan_final_kernel(int* __restrict__ cnt, const int* __restrict__ bbase,
                                  int* __restrict__ offs, int n) {
    __shared__ int sh[SCAN_B];
    int id = (int)(blockIdx.x * SCAN_B + threadIdx.x);
    int v = (id < n) ? cnt[id * CPAD] : 0;
    sh[threadIdx.x] = v;
    __syncthreads();
    for (int off = 1; off < SCAN_B; off <<= 1) {
        int tmp = ((int)threadIdx.x >= off) ? sh[threadIdx.x - off] : 0;
        __syncthreads();
        sh[threadIdx.x] += tmp;
        __syncthreads();
    }
    if (id < n) {
        int excl = sh[threadIdx.x] - v + bbase[blockIdx.x];
        offs[id] = excl;
        cnt[id * CPAD] = excl;   // becomes the scatter cursor
    }
}

__global__ void scatter_kernel(const int* __restrict__ src, const int* __restrict__ dst,
                               const int* __restrict__ et, const float* __restrict__ norm,
                               int* __restrict__ cursor, uint2* __restrict__ rec, int nE) {
    const int r     = (int)blockIdx.x & (NRANGE - 1);
    const int chunk = (int)blockIdx.x >> 3;
    const int nchk  = (int)gridDim.x >> 3;
    const int CH    = (nE + nchk - 1) / nchk;
    const int lo    = r * RANGE;
    const int hi    = (lo + RANGE < NNODES) ? lo + RANGE : NNODES;
    const int e1    = ((chunk + 1) * CH < nE) ? (chunk + 1) * CH : nE;
    for (int e = chunk * CH + (int)threadIdx.x; e < e1; e += 256) {
        const int d = dst[e];
        if (d >= lo && d < hi) {
            int p = atomicAdd(&cursor[d * CPAD], 1);
            rec[p] = make_uint2((uint32_t)src[e] | ((uint32_t)et[e] << 20), asu(norm[e]));
        }
    }
}

// ---------------------------------------------------------------------------
// Input-space aggregation (round-10 measured-improved form):
// HALF-WAVE per dst node; unroll-8 => 16 independent x-gathers per wave in
// flight. coeff staged in LDS. Edge/FMA order identical -> bit-identical G.
// ---------------------------------------------------------------------------
__launch_bounds__(256)
__global__ void csr_agg_kernel(const uint16_t* __restrict__ x,
                               const float* __restrict__ coeff,
                               const int* __restrict__ offs,
                               const uint2* __restrict__ rec,
                               uint16_t* __restrict__ G, int nNodes) {
    __shared__ __align__(16) float cS[NREL * NB];   // 2880 B
    for (int i = (int)threadIdx.x; i < NREL * NB; i += 256) cS[i] = coeff[i];
    __syncthreads();

    const int hl   = (int)threadIdx.x & 31;   // lane within half-wave
    const int hwid = (int)((blockIdx.x * blockDim.x + threadIdx.x) >> 5);
    const int nhw  = (int)((gridDim.x * blockDim.x) >> 5);

    for (int d = hwid; d < nNodes; d += nhw) {
        const int j0 = offs[d], j1 = offs[d + 1];
        float accL[NB] = {0.f, 0.f, 0.f, 0.f, 0.f, 0.f, 0.f, 0.f};  // i = 2*hl
        float accH[NB] = {0.f, 0.f, 0.f, 0.f, 0.f, 0.f, 0.f, 0.f};  // i = 2*hl+1
        int j = j0;
        for (; j + 8 <= j1; j += 8) {
            uint2 r[8];
#pragma unroll
            for (int u = 0; u < 8; u++) r[u] = rec[j + u];
            uint32_t w[8];
#pragma unroll
            for (int u = 0; u < 8; u++)
                w[u] = *reinterpret_cast<const uint32_t*>(
                    x + (size_t)(r[u].x & 0xFFFFFu) * HDIM + 2 * hl);
#pragma unroll
            for (int u = 0; u < 8; u++) {
                const float4 cA = *reinterpret_cast<const float4*>(cS + (r[u].x >> 20) * NB);
                const float4 cB = *reinterpret_cast<const float4*>(cS + (r[u].x >> 20) * NB + 4);
                const float nm = asf(r[u].y);
                fmaC(cA, cB, asf(w[u] << 16) * nm, accL);
                fmaC(cA, cB, asf(w[u] & 0xFFFF0000u) * nm, accH);
            }
        }
        for (; j < j1; j++) {
            const uint2 r0 = rec[j];
            const uint32_t w0 = *reinterpret_cast<const uint32_t*>(
                x + (size_t)(r0.x & 0xFFFFFu) * HDIM + 2 * hl);
            const float4 cA = *reinterpret_cast<const float4*>(cS + (r0.x >> 20) * NB);
            const float4 cB = *reinterpret_cast<const float4*>(cS + (r0.x >> 20) * NB + 4);
            const float nm = asf(r0.y);
            fmaC(cA, cB, asf(w0 << 16) * nm, accL);
            fmaC(cA, cB, asf(w0 & 0xFFFF0000u) * nm, accH);
        }
        // lane hl owns k = 16*hl .. 16*hl+15 (i=2hl -> b0..7, i=2hl+1 -> b0..7)
        uint4 lo, hi;
        lo.x = pack2(accL[0], accL[1]); lo.y = pack2(accL[2], accL[3]);
        lo.z = pack2(accL[4], accL[5]); lo.w = pack2(accL[6], accL[7]);
        hi.x = pack2(accH[0], accH[1]); hi.y = pack2(accH[2], accH[3]);
        hi.z = pack2(accH[4], accH[5]); hi.w = pack2(accH[6], accH[7]);
        uint16_t* gp = G + (size_t)d * KDIM + hl * 16;
        *reinterpret_cast<uint4*>(gp)     = lo;
        *reinterpret_cast<uint4*>(gp + 8) = hi;
    }
}

// ---------------------------------------------------------------------------
// proj_hidden HYBRID (measured good round 15): 256-thread blocks, register
// B-panel per wave (wave = o-tile) + 64-row G tile staged once in XOR-
// swizzled LDS shared by all 4 waves -> G HBM-read 1x.
// ---------------------------------------------------------------------------
__launch_bounds__(256, 2)
__global__ void proj_hidden_kernel(const uint16_t* __restrict__ G,
                                   const float* __restrict__ bases,
                                   const float* __restrict__ bias,
                                   uint16_t* __restrict__ xout, int nNodes) {
    __shared__ __align__(16) uint4 Gs4[64 * 64];   // 64 rows x 64 granules = 64 KB

    const int t    = (int)threadIdx.x;
    const int lane = t & 63;
    const int ot   = t >> 6;            // wave = o-tile (0..3)
    const int q    = lane >> 4;
    const int c    = lane & 15;

    FragU bf[16];
#pragma unroll
    for (int kb = 0; kb < 16; kb++) {
#pragma unroll
        for (int j = 0; j < 8; j++) {
            const int k = kb * 32 + q * 8 + j;
            const int i = k >> 3, b = k & 7;
            bf[kb].s[j] = (short)f2bf(bases[(size_t)(b * HDIM + i) * HDIM + ot * 16 + c]);
        }
    }
    const float bv = bias[ot * 16 + c];

    const int nTiles = (nNodes + 63) / 64;
    for (int tile = (int)blockIdx.x; tile < nTiles; tile += (int)gridDim.x) {
        // ---- stage G tile (64 rows x 1024 B), swizzled granules
        for (int idx = t; idx < 64 * 64; idx += 256) {
            const int row = idx >> 6, g = idx & 63;
            int arow = tile * 64 + row;
            if (arow > nNodes - 1) arow = nNodes - 1;
            Gs4[(row << 6) | (g ^ (row & 7))] =
                *reinterpret_cast<const uint4*>(G + (size_t)arow * KDIM + g * 8);
        }
        __syncthreads();

        // ---- 4 row-groups per wave, A-frags from LDS
#pragma unroll
        for (int g = 0; g < 4; g++) {
            const int row = g * 16 + c;
            f32x4 acc = {0.f, 0.f, 0.f, 0.f};
#pragma unroll
            for (int kb = 0; kb < 16; kb++) {
                FragU a;
                a.u = Gs4[(row << 6) | ((kb * 4 + q) ^ (row & 7))];
                acc = __builtin_amdgcn_mfma_f32_16x16x32_bf16(a.s, bf[kb].s, acc, 0, 0, 0);
            }
            const int nbase = tile * 64 + g * 16 + q * 4;
#pragma unroll
            for (int r = 0; r < 4; r++) {
                const int node = nbase + r;
                if (node < nNodes) {
                    float v = fmaxf(acc[r] + bv, 0.f);
                    xout[(size_t)node * HDIM + ot * 16 + c] = f2bf(v);
                }
            }
        }
        __syncthreads();   // Gs4 reused next tile
    }
}

// ---------------------------------------------------------------------------
// proj_out: register-resident B-panel (measured good): each wave reads
// distinct rows -> G read once. Unchanged.
// ---------------------------------------------------------------------------
__launch_bounds__(256, 3)
__global__ void proj_out_kernel(const uint16_t* __restrict__ G,
                                const float* __restrict__ bases,
                                const float* __restrict__ bias,
                                float* __restrict__ out, int nNodes) {
    const int t    = (int)threadIdx.x;
    const int lane = t & 63;
    const int w    = t >> 6;            // wave = node-group (0..3), single o-tile
    const int q    = lane >> 4;
    const int c    = lane & 15;

    FragU bf[16];
#pragma unroll
    for (int kb = 0; kb < 16; kb++) {
#pragma unroll
        for (int j = 0; j < 8; j++) {
            const int k = kb * 32 + q * 8 + j;
            const int i = k >> 3, b = k & 7;
            bf[kb].s[j] = (short)f2bf(bases[(size_t)(b * HDIM + i) * ODIM + c]);
        }
    }
    const float bv = bias[c];

    const int nTiles = (nNodes + 63) / 64;
    for (int tile = (int)blockIdx.x; tile < nTiles; tile += (int)gridDim.x) {
        int arow = tile * 64 + w * 16 + c;
        if (arow > nNodes - 1) arow = nNodes - 1;
        const uint16_t* gp = G + (size_t)arow * KDIM + q * 8;

        f32x4 acc = {0.f, 0.f, 0.f, 0.f};
#pragma unroll
        for (int kb = 0; kb < 16; kb++) {
            FragU a;
            a.u = *reinterpret_cast<const uint4*>(gp + kb * 32);
            acc = __builtin_amdgcn_mfma_f32_16x16x32_bf16(a.s, bf[kb].s, acc, 0, 0, 0);
        }

        const int nbase = tile * 64 + w * 16 + q * 4;
#pragma unroll
        for (int r = 0; r < 4; r++) {
            const int node = nbase + r;
            if (node < nNodes) out[(size_t)node * ODIM + c] = acc[r] + bv;
        }
    }
}

extern "C" void kernel_launch(void* const* d_in, const int* in_sizes, int n_in,
                              void* d_out, int out_size, void* d_ws, size_t ws_size,
                              hipStream_t stream) {
    const float* feats  = (const float*)d_in[0];
    const float* coeff0 = (const float*)d_in[1];
    const float* bases0 = (const float*)d_in[2];
    const float* bias0  = (const float*)d_in[3];
    const float* coeff1 = (const float*)d_in[4];
    const float* bases1 = (const float*)d_in[5];
    const float* bias1  = (const float*)d_in[6];
    const float* coeff2 = (const float*)d_in[7];
    const float* bases2 = (const float*)d_in[8];
    const float* bias2  = (const float*)d_in[9];
    const int*   src    = (const int*)d_in[10];
    const int*   dst    = (const int*)d_in[11];
    const int*   etype  = (const int*)d_in[12];
    const float* norm   = (const float*)d_in[13];
    float* out = (float*)d_out;

    char* base = (char*)d_ws;
    // layout: G 102.4MB | x 12.8MB | offs | bsum | bbase | rec 8MB
    // Padded cursor (NNODES*CPAD*4 = 6.4MB) ALIASES the start of G: it is
    // dead before csr_agg first writes G (stream-ordered).
    uint16_t* G = (uint16_t*)base;
    int* curs   = (int*)base;                                          // aliased, 6.4MB
    uint16_t* x = (uint16_t*)(base + (size_t)NNODES * KDIM * 2);       // +102,400,000
    const size_t OFF_OFFS  = 115200000;
    const size_t OFF_BSUM  = OFF_OFFS + 800032;
    const size_t OFF_BBASE = OFF_BSUM + 1024;
    const size_t OFF_REC   = OFF_BBASE + 1024;                         // ~116 MB
    int*   offs  = (int*)(base + OFF_OFFS);
    int*   bsum  = (int*)(base + OFF_BSUM);
    int*   bbase = (int*)(base + OFF_BBASE);
    uint2* rec   = (uint2*)(base + OFF_REC);

    const int nblk = (NNODES + SCAN_B - 1) / SCAN_B;   // 196 <= 256

    // ---- CSR build (graph identical across layers; built once per call)
    hipLaunchKernelGGL(zero_kernel, dim3(2048), dim3(256), 0, stream, curs, NNODES * CPAD);
    hipLaunchKernelGGL(hist_kernel, dim3(2048), dim3(256), 0, stream, dst, curs, NEDGES);
    hipLaunchKernelGGL(scan_partial_kernel, dim3(nblk), dim3(SCAN_B), 0, stream, curs, bsum, NNODES);
    hipLaunchKernelGGL(scan_base_kernel, dim3(1), dim3(256), 0, stream, bsum, bbase, offs, nblk, NNODES);
    hipLaunchKernelGGL(scan_final_kernel, dim3(nblk), dim3(SCAN_B), 0, stream, curs, bbase, offs, NNODES);
    hipLaunchKernelGGL(scatter_kernel, dim3(2048), dim3(256), 0, stream,
                       src, dst, etype, norm, curs, rec, NEDGES);

    // ---- x0 = bf16(feats)
    hipLaunchKernelGGL(cast_kernel, dim3(2048), dim3(256), 0, stream,
                       feats, x, NNODES * HDIM / 4);

    // ---- Layer 0
    hipLaunchKernelGGL(csr_agg_kernel, dim3(2048), dim3(256), 0, stream,
                       x, coeff0, offs, rec, G, NNODES);
    hipLaunchKernelGGL(proj_hidden_kernel, dim3(1024), dim3(256), 0, stream,
                       G, bases0, bias0, x, NNODES);
    // ---- Layer 1
    hipLaunchKernelGGL(csr_agg_kernel, dim3(2048), dim3(256), 0, stream,
                       x, coeff1, offs, rec, G, NNODES);
    hipLaunchKernelGGL(proj_hidden_kernel, dim3(1024), dim3(256), 0, stream,
                       G, bases1, bias1, x, NNODES);
    // ---- Layer 2
    hipLaunchKernelGGL(csr_agg_kernel, dim3(2048), dim3(256), 0, stream,
                       x, coeff2, offs, rec, G, NNODES);
    hipLaunchKernelGGL(proj_out_kernel, dim3(1024), dim3(256), 0, stream,
                       G, bases2, bias2, out, NNODES);
}